// Round 21
// baseline (4981.498 us; speedup 1.0000x reference)
//
#include <hip/hip_runtime.h>

// k-means (Lloyd), N=500000 D=64 K=256 ITERS=10, fp32.
// Round 21: per-tile scoring + explicit 2-level prefetch in the 512-thread
// 128-VGPR envelope. Accounting: ~4500 cyc/group-chain = per-tile
// ds_read->MFMA serialization (r12: no regs to prefetch; r17: tight serial).
// Now: acc=f32x4 per tile (r17 semantics, passed), next tile's 4 b128 reads
// issued before current tile's MFMAs, r14 ping-pong group xf prefetch
// (fits now: live ~100 < 128). Numerics identical to r17/r19/r20.

#define D 64
#define K 256
#define ITERS 10
#define BLOCK 512
#define NB_MAX 256
#define EPS 2e-3f
#define SPAD 65
#define PART_STRIDE (K * D + K)   // 16640 floats per block partial
// LDS: chi 32KB + clo 32KB + csq 1KB + sums(padded) 65KB + cnt 1KB = 131KB
#define SMEM_BYTES (32768 * 2 + (256 + 256 * SPAD + 256) * 4)

typedef __attribute__((ext_vector_type(8))) short bf16x8;
typedef __attribute__((ext_vector_type(4))) float f32x4;
typedef __attribute__((ext_vector_type(4))) short short4v;

__device__ __forceinline__ unsigned short f2bf(float f) {
    unsigned u = __builtin_bit_cast(unsigned, f);
    u = u + 0x7FFFu + ((u >> 16) & 1u);   // RNE
    return (unsigned short)(u >> 16);
}
__device__ __forceinline__ float bf2f(unsigned short h) {
    unsigned u = ((unsigned)h) << 16;
    return __builtin_bit_cast(float, u);
}

// ---------------------------------------------------------------------------
__global__ void init_gather(const float* __restrict__ x,
                            const int* __restrict__ idx,
                            float* __restrict__ cent,
                            float* __restrict__ csq) {
    int k = blockIdx.x;
    int d = threadIdx.x;
    float v = x[(size_t)idx[k] * D + d];
    cent[k * D + d] = v;
    float s = v * v;
    #pragma unroll
    for (int off = 32; off > 0; off >>= 1) s += __shfl_down(s, off);
    if (d == 0) csq[k] = s;
}

// ---------------------------------------------------------------------------
// one 16-point group: convert, per-tile MFMA+score (tile-prefetched),
// cross-lane argmin, exact refine, owner-lane LDS accumulate.
__device__ __forceinline__ void process_group(
        const float (&xf)[16], int g, int base, int lim,
        int c15, int g4,
        const short* __restrict__ chi, const short* __restrict__ clo,
        const float* __restrict__ s_csq, float* __restrict__ s_sums,
        float* __restrict__ s_cnt,
        const float* __restrict__ x, const float* __restrict__ cent) {
    int prow = base + g * 16 + c15;
    const bool vA = prow < lim;
    const float* xr = x + (size_t)(vA ? prow : (lim - 1)) * D;

    // ---- hi/lo bf16 fragments of this lane's 16 dims ----
    bf16x8 bh[2], bl[2];
    #pragma unroll
    for (int s = 0; s < 2; ++s) {
        #pragma unroll
        for (int e = 0; e < 8; ++e) {
            float va = xf[s * 8 + e];
            unsigned short ha = f2bf(va);
            bh[s][e] = (short)ha;
            bl[s][e] = (short)f2bf(va - bf2f(ha));
        }
    }

#define AI(s_, t_) ((((s_) * 4 + g4) * 256 + (t_) * 16 + c15) * 8)
    // ---- per-tile MFMA + immediate score, next tile prefetched ----
    float gmin = 3.4e38f;
    int gidx = 0;
    unsigned long long cmask = 0;
    bf16x8 ch0 = *(const bf16x8*)&chi[AI(0, 0)];
    bf16x8 cl0 = *(const bf16x8*)&clo[AI(0, 0)];
    bf16x8 ch1 = *(const bf16x8*)&chi[AI(1, 0)];
    bf16x8 cl1 = *(const bf16x8*)&clo[AI(1, 0)];
    #pragma unroll
    for (int t = 0; t < 16; ++t) {
        bf16x8 nh0, nl0, nh1, nl1;
        if (t < 15) {
            nh0 = *(const bf16x8*)&chi[AI(0, t + 1)];
            nl0 = *(const bf16x8*)&clo[AI(0, t + 1)];
            nh1 = *(const bf16x8*)&chi[AI(1, t + 1)];
            nl1 = *(const bf16x8*)&clo[AI(1, t + 1)];
        }
        f32x4 acc = {0.f, 0.f, 0.f, 0.f};
        acc = __builtin_amdgcn_mfma_f32_16x16x32_bf16(ch0, bh[0], acc, 0, 0, 0);
        acc = __builtin_amdgcn_mfma_f32_16x16x32_bf16(ch0, bl[0], acc, 0, 0, 0);
        acc = __builtin_amdgcn_mfma_f32_16x16x32_bf16(cl0, bh[0], acc, 0, 0, 0);
        acc = __builtin_amdgcn_mfma_f32_16x16x32_bf16(ch1, bh[1], acc, 0, 0, 0);
        acc = __builtin_amdgcn_mfma_f32_16x16x32_bf16(ch1, bl[1], acc, 0, 0, 0);
        acc = __builtin_amdgcn_mfma_f32_16x16x32_bf16(cl1, bh[1], acc, 0, 0, 0);
        f32x4 q = *(const f32x4*)&s_csq[t * 16 + (g4 << 2)];
        #pragma unroll
        for (int r = 0; r < 4; ++r) {
            float sc = acc[r] + q[r];
            int m = t * 16 + (g4 << 2) + r;
            if (sc < gmin) { gmin = sc; gidx = m; }
            if (sc <= gmin + EPS) cmask |= 1ull << (t * 4 + r);  // running-min superset
        }
        ch0 = nh0; cl0 = nl0; ch1 = nh1; cl1 = nl1;
    }
#undef AI

    // ---- cross-lane argmin over the 4 replicas of each point ----
    #pragma unroll
    for (int off = 16; off <= 32; off <<= 1) {
        float so = __shfl_xor(gmin, off);
        int io = __shfl_xor(gidx, off);
        if (so < gmin || (so == gmin && io < gidx)) { gmin = so; gidx = io; }
    }
    int nb_ = __popcll(cmask);
    nb_ += __shfl_xor(nb_, 16);
    nb_ += __shfl_xor(nb_, 32);

    int bk = gidx;
    if (__any(nb_ >= 2)) {
        // exact fp32 refine: reference formula, fp32 centroids
        float xsq = 0.0f;
        #pragma unroll
        for (int d = 0; d < D; ++d) xsq += xr[d] * xr[d];
        float eb = 3.4e38f;
        int em = 0x7fffffff;
        unsigned long long mm = cmask;
        while (mm) {
            int b = __ffsll((unsigned long long)mm) - 1;
            mm &= mm - 1;
            int m = ((b >> 2) << 4) + (g4 << 2) + (b & 3);
            const float* cr = cent + m * D;
            float dot = 0.0f;
            #pragma unroll
            for (int d4 = 0; d4 < D; d4 += 4) {
                float4 c4 = *(const float4*)(cr + d4);
                dot += c4.x * xr[d4 + 0];
                dot += c4.y * xr[d4 + 1];
                dot += c4.z * xr[d4 + 2];
                dot += c4.w * xr[d4 + 3];
            }
            float es = xsq - 2.0f * dot + s_csq[m];
            if (es < eb || (es == eb && m < em)) { eb = es; em = m; }
        }
        #pragma unroll
        for (int off = 16; off <= 32; off <<= 1) {
            float so = __shfl_xor(eb, off);
            int io = __shfl_xor(em, off);
            if (so < eb || (so == eb && io < em)) { eb = so; em = io; }
        }
        bk = em;
    }

    // ---- owner-lane accumulate to LDS ----
    if (vA) {
        #pragma unroll
        for (int s = 0; s < 2; ++s) {
            #pragma unroll
            for (int e = 0; e < 8; ++e)
                atomicAdd(&s_sums[bk * SPAD + s * 32 + g4 * 8 + e],
                          xf[s * 8 + e]);
        }
        if (g4 == 0) atomicAdd(&s_cnt[bk], 1.0f);
    }
}

// ---------------------------------------------------------------------------
// fused assign + accumulate; chi/clo: [8 k-chunks][256 cents][8 elems] (-2c).
__global__ __launch_bounds__(BLOCK, 1) void assign_mfma(
        const float* __restrict__ x,
        const float* __restrict__ cent,
        const float* __restrict__ csq_g,
        float* __restrict__ parts,
        int N, int ppb) {
    extern __shared__ char smem[];
    short* chi = (short*)smem;                       // 16384 shorts
    short* clo = chi + 16384;                        // 16384 shorts
    float* s_csq = (float*)(clo + 16384);            // 256
    float* s_sums = s_csq + 256;                     // 256*SPAD
    float* s_cnt = s_sums + 256 * SPAD;              // 256

    const int tid = threadIdx.x;
    const int wv = tid >> 6;          // 0..7
    const int lane = tid & 63;
    const int c15 = lane & 15;
    const int g4 = lane >> 4;

    const int base = blockIdx.x * ppb;
    int lim = base + ppb;
    if (lim > N) lim = N;
    const int ngroups = (lim > base) ? ((lim - base + 15) >> 4) : 0;

#define LOADX(dst, grp)                                                     \
    {                                                                       \
        int pr_ = base + (grp) * 16 + c15;                                  \
        const float* xp_ =                                                  \
            x + (size_t)((pr_ < lim) ? pr_ : (lim - 1)) * D + g4 * 8;       \
        float4 t0_ = *(const float4*)(xp_);                                 \
        float4 t1_ = *(const float4*)(xp_ + 4);                             \
        float4 t2_ = *(const float4*)(xp_ + 32);                            \
        float4 t3_ = *(const float4*)(xp_ + 36);                            \
        dst[0] = t0_.x;  dst[1] = t0_.y;  dst[2] = t0_.z;  dst[3] = t0_.w;  \
        dst[4] = t1_.x;  dst[5] = t1_.y;  dst[6] = t1_.z;  dst[7] = t1_.w;  \
        dst[8] = t2_.x;  dst[9] = t2_.y;  dst[10] = t2_.z; dst[11] = t2_.w; \
        dst[12] = t3_.x; dst[13] = t3_.y; dst[14] = t3_.z; dst[15] = t3_.w; \
    }

    // ---- prefetch first group's x before staging (hides under staging) ----
    float xfA[16], xfB[16];
    if (wv < ngroups) LOADX(xfA, wv);

    // ---- stage centroids as -2c hi/lo bf16; zero LDS partials ----
    for (int i = tid; i < (K * D) / 4; i += BLOCK) {
        float4 c4 = ((const float4*)cent)[i];
        int elem = i * 4;
        int m = elem >> 6;
        int k0 = elem & 63;
        int g = k0 >> 3, e0 = k0 & 7;
        float cv[4] = {c4.x, c4.y, c4.z, c4.w};
        short4v hv, lv;
        #pragma unroll
        for (int j = 0; j < 4; ++j) {
            float v = -2.0f * cv[j];
            unsigned short h = f2bf(v);
            hv[j] = (short)h;
            lv[j] = (short)f2bf(v - bf2f(h));
        }
        int dst = (g * 256 + m) * 8 + e0;
        *(short4v*)&chi[dst] = hv;
        *(short4v*)&clo[dst] = lv;
    }
    if (tid < K) s_csq[tid] = csq_g[tid];
    for (int i = tid; i < 256 * SPAD; i += BLOCK) s_sums[i] = 0.0f;
    if (tid < K) s_cnt[tid] = 0.0f;
    __syncthreads();

    // ---- ping-pong main loop: 2 groups/iter, group-prefetch depth 1 ----
    #pragma unroll 1
    for (int g = wv; g < ngroups; g += 16) {
        int gB = g + 8;
        bool hB = gB < ngroups;
        if (hB) LOADX(xfB, gB);
        process_group(xfA, g, base, lim, c15, g4,
                      chi, clo, s_csq, s_sums, s_cnt, x, cent);
        if (hB) {
            int gC = gB + 8;
            if (gC < ngroups) LOADX(xfA, gC);
            process_group(xfB, gB, base, lim, c15, g4,
                          chi, clo, s_csq, s_sums, s_cnt, x, cent);
        }
    }
#undef LOADX

    __syncthreads();
    // ---- flush block partials (unpad) ----
    float* part = parts + (size_t)blockIdx.x * PART_STRIDE;
    for (int i = tid; i < K * D; i += BLOCK) {
        int k = i >> 6, d = i & 63;
        part[i] = s_sums[k * SPAD + d];
    }
    if (tid < K) part[K * D + tid] = s_cnt[tid];
}

// ---------------------------------------------------------------------------
// fused reduce + finalize: one cent per block, 256 threads (4 slices x 64 dims)
__global__ void finalize2(float* __restrict__ cent,
                          const float* __restrict__ parts,
                          float* __restrict__ csq_g,
                          int nb) {
    __shared__ float tmp[4][64];
    __shared__ float tcnt[4];
    int k = blockIdx.x;
    int sl = threadIdx.x >> 6;
    int d = threadIdx.x & 63;
    float s = 0.0f, c = 0.0f;
    for (int b = sl; b < nb; b += 4) {
        const float* pb = parts + (size_t)b * PART_STRIDE;
        s += pb[k * D + d];
        c += pb[K * D + k];
    }
    tmp[sl][d] = s;
    if (d == 0) tcnt[sl] = c;
    __syncthreads();
    if (sl == 0) {
        float st = tmp[0][d] + tmp[1][d] + tmp[2][d] + tmp[3][d];
        float ct = tcnt[0] + tcnt[1] + tcnt[2] + tcnt[3];
        float oldc = cent[k * D + d];
        float nc = (ct > 0.0f) ? (st / ct) : oldc;
        cent[k * D + d] = nc;
        float v = nc * nc;
        #pragma unroll
        for (int off = 32; off > 0; off >>= 1) v += __shfl_down(v, off);
        if (d == 0) csq_g[k] = v;
    }
}

// ---------------------------------------------------------------------------
extern "C" void kernel_launch(void* const* d_in, const int* in_sizes, int n_in,
                              void* d_out, int out_size, void* d_ws, size_t ws_size,
                              hipStream_t stream) {
    const float* x = (const float*)d_in[0];
    const int* init_idx = (const int*)d_in[1];

    int N = in_sizes[0] / D;

    float* cent = (float*)d_out;

    // ws layout: parts[nb][PART_STRIDE] | csq[K]
    int nb = NB_MAX;
    size_t need = ((size_t)NB_MAX * PART_STRIDE + K) * sizeof(float);
    if (ws_size < need) {
        size_t avail = (ws_size > (size_t)K * sizeof(float))
                           ? ws_size - (size_t)K * sizeof(float) : 0;
        nb = (int)(avail / (PART_STRIDE * sizeof(float)));
        if (nb < 1) nb = 1;
    }
    float* parts = (float*)d_ws;
    float* csq = parts + (size_t)nb * PART_STRIDE;

    hipFuncSetAttribute(reinterpret_cast<const void*>(assign_mfma),
                        hipFuncAttributeMaxDynamicSharedMemorySize, SMEM_BYTES);

    init_gather<<<dim3(K), dim3(64), 0, stream>>>(x, init_idx, cent, csq);

    int ppb = (N + nb - 1) / nb;
    for (int it = 0; it < ITERS; ++it) {
        assign_mfma<<<dim3(nb), dim3(BLOCK), SMEM_BYTES, stream>>>(
            x, cent, csq, parts, N, ppb);
        finalize2<<<dim3(K), dim3(256), 0, stream>>>(cent, parts, csq, nb);
    }
}

// Round 22
// 2368.385 us; speedup vs baseline: 2.1033x; 2.1033x over previous
//
#include <hip/hip_runtime.h>

// k-means (Lloyd), N=500000 D=64 K=256 ITERS=10, fp32.
// Round 22: FINAL — revert to round 20 (best verified: 2367us, absmax 0.024).
// r21 (per-tile scoring + 2-level prefetch, clean memory) ran 503us/iter:
// per-tile ds_read->MFMA chains serialize regardless of prefetch structure.
// The configuration below (bulk acc[16] MFMA then score, 1024 threads,
// 45% occupancy, LDS-atomic owner-lane accumulation, exact-fp32 refine on
// near-ties) is the empirical optimum of 21 structural variants (~232us/iter;
// insensitive to occupancy/spill/EPS/ILP at HIP source level on this
// toolchain). 3.7x vs round-0 baseline.

#define D 64
#define K 256
#define ITERS 10
#define BLOCK 1024
#define NB_MAX 256
#define EPS 2e-3f
#define SPAD 65
#define PART_STRIDE (K * D + K)   // 16640 floats per block partial
// LDS: chi 32KB + clo 32KB + csq 1KB + sums(padded) 65KB + cnt 1KB = 131KB
#define SMEM_BYTES (32768 * 2 + (256 + 256 * SPAD + 256) * 4)

typedef __attribute__((ext_vector_type(8))) short bf16x8;
typedef __attribute__((ext_vector_type(4))) float f32x4;
typedef __attribute__((ext_vector_type(4))) short short4v;

__device__ __forceinline__ unsigned short f2bf(float f) {
    unsigned u = __builtin_bit_cast(unsigned, f);
    u = u + 0x7FFFu + ((u >> 16) & 1u);   // RNE
    return (unsigned short)(u >> 16);
}
__device__ __forceinline__ float bf2f(unsigned short h) {
    unsigned u = ((unsigned)h) << 16;
    return __builtin_bit_cast(float, u);
}

// ---------------------------------------------------------------------------
__global__ void init_gather(const float* __restrict__ x,
                            const int* __restrict__ idx,
                            float* __restrict__ cent,
                            float* __restrict__ csq) {
    int k = blockIdx.x;
    int d = threadIdx.x;
    float v = x[(size_t)idx[k] * D + d];
    cent[k * D + d] = v;
    float s = v * v;
    #pragma unroll
    for (int off = 32; off > 0; off >>= 1) s += __shfl_down(s, off);
    if (d == 0) csq[k] = s;
}

// ---------------------------------------------------------------------------
// score -> argmin (+ exact fp32 refine on near-ties).
__device__ __forceinline__ int resolve_bk(
        const f32x4 (&acc)[16], const float* __restrict__ s_csq,
        const float* __restrict__ cent, const float* __restrict__ xr,
        int g4) {
    // pass 1: global approx min
    float gmin = 3.4e38f;
    int gidx = 0;
    #pragma unroll
    for (int t = 0; t < 16; ++t) {
        f32x4 q = *(const f32x4*)&s_csq[t * 16 + (g4 << 2)];
        #pragma unroll
        for (int r = 0; r < 4; ++r) {
            float sc = acc[t][r] + q[r];
            int m = t * 16 + (g4 << 2) + r;
            if (sc < gmin) { gmin = sc; gidx = m; }
        }
    }
    #pragma unroll
    for (int off = 16; off <= 32; off <<= 1) {
        float so = __shfl_xor(gmin, off);
        int io = __shfl_xor(gidx, off);
        if (so < gmin || (so == gmin && io < gidx)) { gmin = so; gidx = io; }
    }
    // pass 2: candidate mask vs FINAL min
    unsigned long long cmask = 0;
    #pragma unroll
    for (int t = 0; t < 16; ++t) {
        f32x4 q = *(const f32x4*)&s_csq[t * 16 + (g4 << 2)];
        #pragma unroll
        for (int r = 0; r < 4; ++r) {
            float sc = acc[t][r] + q[r];
            if (sc <= gmin + EPS) cmask |= 1ull << (t * 4 + r);
        }
    }
    int nb_ = __popcll(cmask);
    nb_ += __shfl_xor(nb_, 16);
    nb_ += __shfl_xor(nb_, 32);

    int bk = gidx;
    if (__any(nb_ >= 2)) {
        float xsq = 0.0f;
        #pragma unroll
        for (int d = 0; d < D; ++d) xsq += xr[d] * xr[d];
        float eb = 3.4e38f;
        int em = 0x7fffffff;
        unsigned long long mm = cmask;
        while (mm) {
            int b = __ffsll((unsigned long long)mm) - 1;
            mm &= mm - 1;
            int m = ((b >> 2) << 4) + (g4 << 2) + (b & 3);
            const float* cr = cent + m * D;
            float dot = 0.0f;
            #pragma unroll
            for (int d4 = 0; d4 < D; d4 += 4) {
                float4 c4 = *(const float4*)(cr + d4);
                dot += c4.x * xr[d4 + 0];
                dot += c4.y * xr[d4 + 1];
                dot += c4.z * xr[d4 + 2];
                dot += c4.w * xr[d4 + 3];
            }
            float es = xsq - 2.0f * dot + s_csq[m];
            if (es < eb || (es == eb && m < em)) { eb = es; em = m; }
        }
        #pragma unroll
        for (int off = 16; off <= 32; off <<= 1) {
            float so = __shfl_xor(eb, off);
            int io = __shfl_xor(em, off);
            if (so < eb || (so == eb && io < em)) { eb = so; em = io; }
        }
        bk = em;
    }
    return bk;
}

// ---------------------------------------------------------------------------
// fused assign (MFMA + exact refine) + owner-lane LDS accumulate.
// chi/clo LDS layout: [8 k-chunks][256 cents][8 elems] bf16 of (-2*c).
__global__ __launch_bounds__(BLOCK, 4) void assign_mfma(
        const float* __restrict__ x,
        const float* __restrict__ cent,
        const float* __restrict__ csq_g,
        float* __restrict__ parts,
        int N, int ppb) {
    extern __shared__ char smem[];
    short* chi = (short*)smem;                       // 16384 shorts
    short* clo = chi + 16384;                        // 16384 shorts
    float* s_csq = (float*)(clo + 16384);            // 256
    float* s_sums = s_csq + 256;                     // 256*SPAD
    float* s_cnt = s_sums + 256 * SPAD;              // 256

    const int tid = threadIdx.x;

    // ---- stage centroids as -2c hi/lo bf16; zero LDS partials ----
    for (int i = tid; i < (K * D) / 4; i += BLOCK) {
        float4 c4 = ((const float4*)cent)[i];
        int elem = i * 4;
        int m = elem >> 6;
        int k0 = elem & 63;
        int g = k0 >> 3, e0 = k0 & 7;
        float cv[4] = {c4.x, c4.y, c4.z, c4.w};
        short4v hv, lv;
        #pragma unroll
        for (int j = 0; j < 4; ++j) {
            float v = -2.0f * cv[j];
            unsigned short h = f2bf(v);
            hv[j] = (short)h;
            lv[j] = (short)f2bf(v - bf2f(h));
        }
        int dst = (g * 256 + m) * 8 + e0;
        *(short4v*)&chi[dst] = hv;
        *(short4v*)&clo[dst] = lv;
    }
    if (tid < K) s_csq[tid] = csq_g[tid];
    for (int i = tid; i < 256 * SPAD; i += BLOCK) s_sums[i] = 0.0f;
    if (tid < K) s_cnt[tid] = 0.0f;
    __syncthreads();

    const int wv = tid >> 6;          // 0..15
    const int lane = tid & 63;
    const int c15 = lane & 15;        // point-in-group / cent-row-in-tile
    const int g4 = lane >> 4;         // k-chunk group / cent quadrant

    const int base = blockIdx.x * ppb;
    int lim = base + ppb;
    if (lim > N) lim = N;
    const int ngroups = (lim > base) ? ((lim - base + 15) >> 4) : 0;

    #pragma unroll 1
    for (int g0 = wv; g0 < ngroups; g0 += 16) {
        int prow = base + g0 * 16 + c15;
        const bool vA = prow < lim;
        const float* xr = x + (size_t)(vA ? prow : (lim - 1)) * D;

        // ---- this lane's 16 dims of its point + hi/lo bf16 fragments ----
        float xf[16];
        bf16x8 bh[2], bl[2];
        #pragma unroll
        for (int s = 0; s < 2; ++s) {
            const float4* pa = (const float4*)(xr + s * 32 + g4 * 8);
            float4 a0 = pa[0], a1 = pa[1];
            xf[s * 8 + 0] = a0.x; xf[s * 8 + 1] = a0.y;
            xf[s * 8 + 2] = a0.z; xf[s * 8 + 3] = a0.w;
            xf[s * 8 + 4] = a1.x; xf[s * 8 + 5] = a1.y;
            xf[s * 8 + 6] = a1.z; xf[s * 8 + 7] = a1.w;
        }
        #pragma unroll
        for (int s = 0; s < 2; ++s) {
            #pragma unroll
            for (int e = 0; e < 8; ++e) {
                float va = xf[s * 8 + e];
                unsigned short ha = f2bf(va);
                bh[s][e] = (short)ha;
                bl[s][e] = (short)f2bf(va - bf2f(ha));
            }
        }

        // ---- 16 cent-tiles of MFMA ----
        f32x4 acc[16];
        #pragma unroll
        for (int t = 0; t < 16; ++t) {
            f32x4 z = {0.f, 0.f, 0.f, 0.f};
            acc[t] = z;
            #pragma unroll
            for (int s = 0; s < 2; ++s) {
                int ai = (((s * 4 + g4) * 256) + t * 16 + c15) * 8;
                bf16x8 ah = *(const bf16x8*)&chi[ai];
                bf16x8 al = *(const bf16x8*)&clo[ai];
                acc[t] = __builtin_amdgcn_mfma_f32_16x16x32_bf16(ah, bh[s], acc[t], 0, 0, 0);
                acc[t] = __builtin_amdgcn_mfma_f32_16x16x32_bf16(ah, bl[s], acc[t], 0, 0, 0);
                acc[t] = __builtin_amdgcn_mfma_f32_16x16x32_bf16(al, bh[s], acc[t], 0, 0, 0);
            }
        }

        // ---- argmin (+refine), then owner-lane accumulate to LDS ----
        int bk = resolve_bk(acc, s_csq, cent, xr, g4);
        if (vA) {
            #pragma unroll
            for (int s = 0; s < 2; ++s) {
                #pragma unroll
                for (int e = 0; e < 8; ++e)
                    atomicAdd(&s_sums[bk * SPAD + s * 32 + g4 * 8 + e],
                              xf[s * 8 + e]);
            }
            if (g4 == 0) atomicAdd(&s_cnt[bk], 1.0f);
        }
    }

    __syncthreads();
    // ---- flush block partials (unpad) ----
    float* part = parts + (size_t)blockIdx.x * PART_STRIDE;
    for (int i = tid; i < K * D; i += BLOCK) {
        int k = i >> 6, d = i & 63;
        part[i] = s_sums[k * SPAD + d];
    }
    if (tid < K) part[K * D + tid] = s_cnt[tid];
}

// ---------------------------------------------------------------------------
// fused reduce + finalize: one cent per block, 256 threads (4 slices x 64 dims)
__global__ void finalize2(float* __restrict__ cent,
                          const float* __restrict__ parts,
                          float* __restrict__ csq_g,
                          int nb) {
    __shared__ float tmp[4][64];
    __shared__ float tcnt[4];
    int k = blockIdx.x;
    int sl = threadIdx.x >> 6;
    int d = threadIdx.x & 63;
    float s = 0.0f, c = 0.0f;
    for (int b = sl; b < nb; b += 4) {
        const float* pb = parts + (size_t)b * PART_STRIDE;
        s += pb[k * D + d];
        c += pb[K * D + k];
    }
    tmp[sl][d] = s;
    if (d == 0) tcnt[sl] = c;
    __syncthreads();
    if (sl == 0) {
        float st = tmp[0][d] + tmp[1][d] + tmp[2][d] + tmp[3][d];
        float ct = tcnt[0] + tcnt[1] + tcnt[2] + tcnt[3];
        float oldc = cent[k * D + d];
        float nc = (ct > 0.0f) ? (st / ct) : oldc;
        cent[k * D + d] = nc;
        float v = nc * nc;
        #pragma unroll
        for (int off = 32; off > 0; off >>= 1) v += __shfl_down(v, off);
        if (d == 0) csq_g[k] = v;
    }
}

// ---------------------------------------------------------------------------
extern "C" void kernel_launch(void* const* d_in, const int* in_sizes, int n_in,
                              void* d_out, int out_size, void* d_ws, size_t ws_size,
                              hipStream_t stream) {
    const float* x = (const float*)d_in[0];
    const int* init_idx = (const int*)d_in[1];

    int N = in_sizes[0] / D;

    float* cent = (float*)d_out;

    // ws layout: parts[nb][PART_STRIDE] | csq[K]
    int nb = NB_MAX;
    size_t need = ((size_t)NB_MAX * PART_STRIDE + K) * sizeof(float);
    if (ws_size < need) {
        size_t avail = (ws_size > (size_t)K * sizeof(float))
                           ? ws_size - (size_t)K * sizeof(float) : 0;
        nb = (int)(avail / (PART_STRIDE * sizeof(float)));
        if (nb < 1) nb = 1;
    }
    float* parts = (float*)d_ws;
    float* csq = parts + (size_t)nb * PART_STRIDE;

    hipFuncSetAttribute(reinterpret_cast<const void*>(assign_mfma),
                        hipFuncAttributeMaxDynamicSharedMemorySize, SMEM_BYTES);

    init_gather<<<dim3(K), dim3(64), 0, stream>>>(x, init_idx, cent, csq);

    int ppb = (N + nb - 1) / nb;
    for (int it = 0; it < ITERS; ++it) {
        assign_mfma<<<dim3(nb), dim3(BLOCK), SMEM_BYTES, stream>>>(
            x, cent, csq, parts, N, ppb);
        finalize2<<<dim3(K), dim3(256), 0, stream>>>(cent, parts, csq, nb);
    }
}